// Round 1
// baseline (869.431 us; speedup 1.0000x reference)
//
#include <hip/hip_runtime.h>
#include <math.h>

#define DIM 256
#define HEADS 8
#define HD 32
#define T 1600
#define B 8
#define NBH (B * HEADS)
#define SCALE 0.17677669529663687f
#define EPS 1e-6f

// ---------------- Kernel 0: transpose first 512 rows of qkv_w ----------------
// W: (768, 256) row-major.  Wt: (256, 512), Wt[c*512 + r] = W[r*256 + c], r<512.
__global__ __launch_bounds__(256) void transpose_w(const float* __restrict__ W,
                                                   float* __restrict__ Wt) {
    int idx = blockIdx.x * 256 + threadIdx.x;  // 0 .. 512*256-1
    int r = idx & 511;                         // lane-consecutive -> coalesced store
    int c = idx >> 9;
    Wt[c * 512 + r] = W[r * 256 + c];
}

// ---------------- Kernel A: LayerNorm + QKV projection (q,k only) ----------------
// feat: (B, DIM, T) flat. Produces:
//   qws[((b*8+h)*T + t)*32 + d] = (q + bias) * SCALE      (row-major q)
//   ktws[((b*8+h)*32 + d)*T + t] = k + bias               (d-major k for coalesced reads)
#define TOK 32
__global__ __launch_bounds__(256) void ln_qkv(const float* __restrict__ feat,
                                              const float* __restrict__ lnw,
                                              const float* __restrict__ lnb,
                                              const float* __restrict__ qkvb,
                                              const float* __restrict__ Wt,
                                              float* __restrict__ qws,
                                              float* __restrict__ ktws) {
    __shared__ float x[DIM * TOK];      // x[c][t'], 32 KB
    __shared__ float red[2][8][TOK];    // partial sum / sumsq
    __shared__ float mus[TOK], rstd[TOK];

    const int tid = threadIdx.x;
    const int blk = blockIdx.x;               // 0..399
    const int b = blk / (T / TOK);            // /50
    const int t0 = (blk % (T / TOK)) * TOK;
    const int tp = tid & 31;                  // token within tile
    const int g = tid >> 5;                   // 0..7

    const float* fb = feat + (size_t)b * DIM * T + t0;

    // load 32 tokens x 256 channels, coalesced along t
    for (int cc = 0; cc < DIM; cc += 8) {
        int c = cc + g;
        x[c * TOK + tp] = fb[(size_t)c * T + tp];
    }
    __syncthreads();

    // LN stats: thread (g, tp) sums 32 channels of token tp
    float s = 0.f, sq = 0.f;
    for (int i = 0; i < 32; ++i) {
        float v = x[(g * 32 + i) * TOK + tp];
        s += v;
        sq += v * v;
    }
    red[0][g][tp] = s;
    red[1][g][tp] = sq;
    __syncthreads();
    if (tid < TOK) {
        float ts = 0.f, tq = 0.f;
        for (int i = 0; i < 8; ++i) { ts += red[0][i][tid]; tq += red[1][i][tid]; }
        float mu = ts * (1.f / DIM);
        float var = tq * (1.f / DIM) - mu * mu;
        mus[tid] = mu;
        rstd[tid] = rsqrtf(var + EPS);
    }
    __syncthreads();

    // normalize in LDS
    for (int cc = 0; cc < DIM; cc += 8) {
        int c = cc + g;
        float w = lnw[c];
        float bb = lnb[c];
        float v = x[c * TOK + tp];
        x[c * TOK + tp] = (v - mus[tp]) * rstd[tp] * w + bb;
    }
    __syncthreads();

    // GEMM: thread tid computes q-row tid and k-row tid (W rows tid and tid+256)
    // for all 32 tokens. Wt loads coalesced; x reads are LDS broadcasts.
    float accq[TOK], acck[TOK];
#pragma unroll
    for (int t = 0; t < TOK; ++t) { accq[t] = 0.f; acck[t] = 0.f; }

    for (int c = 0; c < DIM; ++c) {
        float wq = Wt[c * 512 + tid];
        float wk = Wt[c * 512 + 256 + tid];
        const float* xr = &x[c * TOK];
#pragma unroll
        for (int t = 0; t < TOK; ++t) {
            float xv = xr[t];
            accq[t] += wq * xv;
            acck[t] += wk * xv;
        }
    }

    const float bq = qkvb[tid];
    const float bk = qkvb[256 + tid];
    const int h = tid >> 5;
    const int d = tid & 31;

    float* qp = qws + ((size_t)(b * HEADS + h) * T + t0) * HD + d;
#pragma unroll
    for (int t = 0; t < TOK; ++t) qp[(size_t)t * HD] = (accq[t] + bq) * SCALE;

    float* kp = ktws + ((size_t)(b * HEADS + h) * HD + d) * T + t0;
#pragma unroll
    for (int t = 0; t < TOK; ++t) kp[t] = acck[t] + bk;
}

// ---------------- Kernel B: scores + softmax ----------------
// One block = 8 query rows of one (b,h); full 1600 cols held in registers
// (8 rows x 7 chunks of 256 = 56 accs/thread).
#define ROWS 8
#define JJ 7  // ceil(1600/256)
__global__ __launch_bounds__(256) void attn_softmax(const float* __restrict__ qws,
                                                    const float* __restrict__ ktws,
                                                    float* __restrict__ out) {
    __shared__ float qs[HD][ROWS];  // transposed q tile, rows 32B each -> float4-able
    __shared__ float redm[4][ROWS], redl[4][ROWS];

    const int tid = threadIdx.x;
    const int blk = blockIdx.x;               // 0..12799
    const int bh = blk / (T / ROWS);          // /200
    const int r0 = (blk % (T / ROWS)) * ROWS;

    {
        int i = tid >> 5, d = tid & 31;       // 256 threads = 8 rows x 32 d
        qs[d][i] = qws[((size_t)bh * T + r0 + i) * HD + d];
    }
    __syncthreads();

    float acc[ROWS][JJ];
#pragma unroll
    for (int i = 0; i < ROWS; ++i)
#pragma unroll
        for (int jj = 0; jj < JJ; ++jj) acc[i][jj] = 0.f;

    const bool v6 = tid < (T - 6 * 256);      // tid < 64: chunk 6 valid
    const float* kb = ktws + (size_t)bh * HD * T;

    for (int d = 0; d < HD; ++d) {
        const float4* q4 = (const float4*)&qs[d][0];
        float4 qa = q4[0];
        float4 qb = q4[1];
        const float* kr = kb + d * T;
#pragma unroll
        for (int jj = 0; jj < JJ; ++jj) {
            int j = tid + jj * 256;
            float kv = (jj < 6 || v6) ? kr[j < T ? j : 0] : 0.f;
            acc[0][jj] += qa.x * kv;
            acc[1][jj] += qa.y * kv;
            acc[2][jj] += qa.z * kv;
            acc[3][jj] += qa.w * kv;
            acc[4][jj] += qb.x * kv;
            acc[5][jj] += qb.y * kv;
            acc[6][jj] += qb.z * kv;
            acc[7][jj] += qb.w * kv;
        }
    }

    const int w = tid >> 6;
    const int lane = tid & 63;

    // row max
#pragma unroll
    for (int i = 0; i < ROWS; ++i) {
        float v = -3e38f;
#pragma unroll
        for (int jj = 0; jj < 6; ++jj) v = fmaxf(v, acc[i][jj]);
        if (v6) v = fmaxf(v, acc[i][6]);
#pragma unroll
        for (int off = 32; off; off >>= 1) v = fmaxf(v, __shfl_xor(v, off, 64));
        if (lane == 0) redm[w][i] = v;
    }
    __syncthreads();
    float m[ROWS];
#pragma unroll
    for (int i = 0; i < ROWS; ++i)
        m[i] = fmaxf(fmaxf(redm[0][i], redm[1][i]), fmaxf(redm[2][i], redm[3][i]));
    __syncthreads();

    // exp + row sum
#pragma unroll
    for (int i = 0; i < ROWS; ++i) {
        float s = 0.f;
#pragma unroll
        for (int jj = 0; jj < JJ; ++jj) {
            float p = __expf(acc[i][jj] - m[i]);
            if (jj == 6 && !v6) p = 0.f;
            acc[i][jj] = p;
            s += p;
        }
#pragma unroll
        for (int off = 32; off; off >>= 1) s += __shfl_xor(s, off, 64);
        if (lane == 0) redl[w][i] = s;
    }
    __syncthreads();
    float rinv[ROWS];
#pragma unroll
    for (int i = 0; i < ROWS; ++i)
        rinv[i] = 1.0f / (redl[0][i] + redl[1][i] + redl[2][i] + redl[3][i]);

    // store
    float* ob = out + (size_t)bh * T * T + (size_t)r0 * T;
#pragma unroll
    for (int i = 0; i < ROWS; ++i) {
#pragma unroll
        for (int jj = 0; jj < JJ; ++jj) {
            int j = tid + jj * 256;
            if (jj < 6 || v6) ob[(size_t)i * T + j] = acc[i][jj] * rinv[i];
        }
    }
}

// ---------------- launch ----------------
extern "C" void kernel_launch(void* const* d_in, const int* in_sizes, int n_in,
                              void* d_out, int out_size, void* d_ws, size_t ws_size,
                              hipStream_t stream) {
    const float* feat = (const float*)d_in[0];
    const float* lnw = (const float*)d_in[1];
    const float* lnb = (const float*)d_in[2];
    const float* qkvw = (const float*)d_in[3];
    const float* qkvb = (const float*)d_in[4];
    float* out = (float*)d_out;

    float* Wt = (float*)d_ws;                        // 256*512 floats = 512 KB
    float* qws = Wt + 256 * 512;                     // NBH*T*HD = 3,276,800 floats
    float* ktws = qws + (size_t)NBH * T * HD;        // same size

    transpose_w<<<512, 256, 0, stream>>>(qkvw, Wt);
    ln_qkv<<<(B * T) / TOK, 256, 0, stream>>>(feat, lnw, lnb, qkvb, Wt, qws, ktws);
    attn_softmax<<<NBH * (T / ROWS), 256, 0, stream>>>(qws, ktws, out);
}